// Round 13
// baseline (255.961 us; speedup 1.0000x reference)
//
#include <hip/hip_runtime.h>
#include <hip/hip_bf16.h>

// Problem constants
#define N_TOT 32768
#define G 4
#define DIM 128
#define CB 512

// Output layout (floats)
#define XHAT_OFF   0
#define ONEHOT_OFF ((size_t)N_TOT * G * DIM)                      // 16777216
#define IDX_OFF    (ONEHOT_OFF + (size_t)N_TOT * G * CB)          // 83886080

// Workspace layout (bytes)
// cbf layout: [g][colblk(16)][ks(8)][h(2)][col(32)][e(8)] fp16
#define CB2_BYTES    ((size_t)G * CB * 4)                          // 8192
#define CBH_OFF      CB2_BYTES
#define CBHALF_BYTES ((size_t)G * CB * DIM * 2)                    // 524288
#define CBL_OFF      (CBH_OFF + CBHALF_BYTES)
#define PVAL_OFF     (CBL_OFF + CBHALF_BYTES)                      // 1056768
#define PART_BYTES   ((size_t)4 * G * N_TOT * 4)                   // 2 MB
#define PIDX_OFF     (PVAL_OFF + PART_BYTES)
#define WS_NEED      (PIDX_OFF + PART_BYTES)                       // ~5.25 MB

typedef _Float16 half8    __attribute__((ext_vector_type(8)));
typedef float    floatx16 __attribute__((ext_vector_type(16)));
typedef float    floatx4  __attribute__((ext_vector_type(4)));

// fp32 -> (hi,lo) fp16 RN split. f = hi + lo + err, |err| <= 2^-22 |f|.
__device__ __forceinline__ void split8(floatx4 v0, floatx4 v1, half8& hi, half8& lo) {
    float f[8] = {v0.x, v0.y, v0.z, v0.w, v1.x, v1.y, v1.z, v1.w};
#pragma unroll
    for (int e = 0; e < 8; ++e) {
        _Float16 h = (_Float16)f[e];
        hi[e] = h;
        lo[e] = (_Float16)(f[e] - (float)h);
    }
}

// ---------------------------------------------------------------------------
// Prep 1: cb2h[g*CB+k] = 0.5*sum_d cb[g][k][d]^2  (validated since round 1)
// ---------------------------------------------------------------------------
__global__ void cvq_cb2_kernel(const float* __restrict__ cb, float* __restrict__ cb2h) {
    int i = blockIdx.x * 256 + threadIdx.x;
    if (i >= G * CB) return;
    const float4* p = (const float4*)&cb[(size_t)i * DIM];
    float s = 0.f;
#pragma unroll
    for (int j = 0; j < DIM / 4; ++j) {
        float4 v = p[j];
        s += v.x * v.x + v.y * v.y + v.z * v.z + v.w * v.w;
    }
    cb2h[i] = 0.5f * s;
}

// ---------------------------------------------------------------------------
// Prep 2: pack codebook into MFMA-fragment order, split hi/lo (validated r8).
// ---------------------------------------------------------------------------
__global__ void cvq_cbpack_kernel(const float* __restrict__ cb,
                                  _Float16* __restrict__ cbfh, _Float16* __restrict__ cbfl) {
    int t = blockIdx.x * 256 + threadIdx.x;    // 0..32767
    int col    = t & 31;
    int h      = (t >> 5) & 1;
    int ks     = (t >> 6) & 7;
    int colblk = (t >> 9) & 15;
    int g      = t >> 13;
    const float* src = &cb[((size_t)(g * CB + colblk * 32 + col)) * DIM + ks * 16 + h * 8];
    half8 hi, lo;
    split8(*(const floatx4*)src, *(const floatx4*)(src + 4), hi, lo);
    *(half8*)&cbfh[(size_t)t * 8] = hi;
    *(half8*)&cbfl[(size_t)t * 8] = lo;
}

// ---------------------------------------------------------------------------
// Phase 1: argmin partials. Block = (1/4 of codebook, one g); grid (64, G, 4).
// cb quarter (4 colblks, hi+lo = 64 KB) staged ONCE into LDS; then 4 waves run
// BARRIER-FREE: wave w sweeps 4 row-tiles of 32 rows (512 rows/block), x read
// directly from global (r4-validated A-frag pattern), cb from LDS (linear
// lane*16 b128 reads, conflict-free). Writes per-row (val, idx) partials.
// score = 0.5*cb2[k] - cross ; k = q*128 + t*32 + col (ascending in q,t).
// Fragment layouts (gfx950 32x32x16, validated rounds 4-12):
//   A: lane l, elem e: row=l&31, k=(l>>5)*8+e ; B: col=l&31, same k
//   C: lane l, reg r:  col=l&31, row=(r&3)+8*(r>>2)+4*(l>>5)
// ---------------------------------------------------------------------------
__global__ __launch_bounds__(256, 2) void cvq_phase1_kernel(
        const float* __restrict__ x,
        const _Float16* __restrict__ cbfh, const _Float16* __restrict__ cbfl,
        const float* __restrict__ cb2h,
        float* __restrict__ pval, int* __restrict__ pidx) {

    __shared__ _Float16 lh[16384];   // 32 KB: quarter, hi plane
    __shared__ _Float16 ll[16384];   // 32 KB: quarter, lo plane

    const int bx   = blockIdx.x;      // 0..63 -> rows bx*512..+511
    const int g    = blockIdx.y;
    const int q    = blockIdx.z;      // quarter -> cols q*128..+127
    const int tid  = threadIdx.x;
    const int wid  = tid >> 6;
    const int lane = tid & 63;
    const int col  = lane & 31;
    const int h    = lane >> 5;

    // ---- stage cb quarter: contiguous 16384 halfs per plane, coalesced ----
    const size_t base = ((size_t)g * 16 + q * 4) * 4096;
#pragma unroll
    for (int i = 0; i < 8; ++i) {
        int t = tid + i * 256;        // half8 index 0..2047
        *(half8*)&lh[(size_t)t * 8] = *(const half8*)&cbfh[base + (size_t)t * 8];
        *(half8*)&ll[(size_t)t * 8] = *(const half8*)&cbfl[base + (size_t)t * 8];
    }
    __syncthreads();                  // ONLY barrier in this kernel

    float c2v[4];
#pragma unroll
    for (int t = 0; t < 4; ++t)
        c2v[t] = cb2h[g * CB + q * 128 + t * 32 + col];

    const size_t pbase = ((size_t)q * G + g) * N_TOT;

    for (int it = 0; it < 4; ++it) {
        const int n0 = bx * 512 + it * 128 + wid * 32;   // wave's row base
        const float* xr = &x[(((size_t)(n0 + col)) * G + g) * DIM + h * 8];

        floatx16 acc[4] = {};   // [ntile] fp32 accumulators = cross
#pragma unroll
        for (int ks = 0; ks < 8; ++ks) {
            const int d = ks * 16;
            half8 ah, al;
            split8(*(const floatx4*)(xr + d), *(const floatx4*)(xr + d + 4), ah, al);
#pragma unroll
            for (int t = 0; t < 4; ++t) {
                const int o = (t * 4096 + ks * 512) + lane * 8;
                half8 bh = *(const half8*)&lh[o];
                half8 bl = *(const half8*)&ll[o];
                acc[t] = __builtin_amdgcn_mfma_f32_32x32x16_f16(ah, bh, acc[t], 0, 0, 0);
                acc[t] = __builtin_amdgcn_mfma_f32_32x32x16_f16(ah, bl, acc[t], 0, 0, 0);
                acc[t] = __builtin_amdgcn_mfma_f32_32x32x16_f16(al, bh, acc[t], 0, 0, 0);
            }
        }

        // ---- per-row argmin over this quarter's 128 cols (validated r7/r8) ----
#pragma unroll
        for (int r = 0; r < 16; ++r) {
            const int row = (r & 3) + 8 * (r >> 2) + 4 * h;   // 0..31
            float bv = c2v[0] - acc[0][r];
            int   bi = q * 128 + col;
#pragma unroll
            for (int t = 1; t < 4; ++t) {
                float sc = c2v[t] - acc[t][r];
                int   kk = q * 128 + t * 32 + col;
                if (sc < bv) { bv = sc; bi = kk; }            // k ascending in t
            }
#pragma unroll
            for (int off = 1; off < 32; off <<= 1) {          // stays in 32-half
                float ov = __shfl_xor(bv, off);
                int   oi = __shfl_xor(bi, off);
                if (ov < bv || (ov == bv && oi < bi)) { bv = ov; bi = oi; }
            }
            if (col == 0) {
                const size_t n = (size_t)n0 + row;
                pval[pbase + n] = bv;
                pidx[pbase + n] = bi;
            }
        }
    }
}

// ---------------------------------------------------------------------------
// Phase 2: combine quarters + epilogue (r8-validated shape). Block = 64 rows
// x one g, grid (512, G). Ascending q = ascending k; strict < keeps numpy
// first-min. Streams idx + x_hat + full one_hot (nontemporal).
// ---------------------------------------------------------------------------
__global__ __launch_bounds__(256, 4) void cvq_phase2_kernel(
        const float* __restrict__ pval, const int* __restrict__ pidx,
        const float* __restrict__ cb, float* __restrict__ out) {

    __shared__ int idxs[64];

    const int n0  = blockIdx.x * 64;
    const int g   = blockIdx.y;
    const int tid = threadIdx.x;

    if (tid < 64) {
        const size_t n = (size_t)n0 + tid;
        float bv = pval[((size_t)0 * G + g) * N_TOT + n];
        int   bi = pidx[((size_t)0 * G + g) * N_TOT + n];
#pragma unroll
        for (int qq = 1; qq < 4; ++qq) {
            float pv = pval[((size_t)qq * G + g) * N_TOT + n];
            int   pi = pidx[((size_t)qq * G + g) * N_TOT + n];
            if (pv < bv) { bv = pv; bi = pi; }   // ascending q => ascending k
        }
        idxs[tid] = bi;
        out[IDX_OFF + n * G + g] = (float)bi;
    }
    __syncthreads();

    float* out_xhat = out + XHAT_OFF;
    float* out_oh   = out + ONEHOT_OFF;

    // ---- x_hat: 64 rows x 32 float4, gathered from codebook (L2-hot) ----
#pragma unroll
    for (int p = 0; p < 8; ++p) {
        int t  = tid + p * 256;
        int r  = t >> 5;
        int d4 = (t & 31) << 2;
        int k  = idxs[r];
        floatx4 v = *(const floatx4*)&cb[((size_t)g * CB + k) * DIM + d4];
        __builtin_nontemporal_store(v, (floatx4*)&out_xhat[(((size_t)(n0 + r)) * G + g) * DIM + d4]);
    }

    // ---- one_hot: 64 rows x 128 float4, fused zero-fill, streaming stores ----
#pragma unroll
    for (int p = 0; p < 32; ++p) {
        int t  = tid + p * 256;
        int r  = t >> 7;
        int k4 = (t & 127) << 2;
        int k  = idxs[r];
        floatx4 v;
        v.x = (k4 + 0 == k) ? 1.f : 0.f;
        v.y = (k4 + 1 == k) ? 1.f : 0.f;
        v.z = (k4 + 2 == k) ? 1.f : 0.f;
        v.w = (k4 + 3 == k) ? 1.f : 0.f;
        __builtin_nontemporal_store(v, (floatx4*)&out_oh[(((size_t)(n0 + r)) * G + g) * CB + k4]);
    }
}

// ---------------------------------------------------------------------------
// FALLBACK (validated round-4 path, needs only 8KB ws): in-kernel splits.
// ---------------------------------------------------------------------------
#define FBM 64
__global__ __launch_bounds__(256, 2) void cvq_main_kernel(
        const float* __restrict__ x,
        const float* __restrict__ cb,
        const float* __restrict__ cb2h,
        float* __restrict__ out) {

    __shared__ float part_v[4][FBM];
    __shared__ int   part_i[4][FBM];
    __shared__ int   idxs[FBM];

    const int n0   = blockIdx.x * FBM;
    const int g    = blockIdx.y;
    const int tid  = threadIdx.x;
    const int wid  = tid >> 6;
    const int lane = tid & 63;
    const int col  = lane & 31;
    const int h    = lane >> 5;
    const int klo  = h * 8;

    const float* xr0 = &x[(((size_t)(n0 + col)) * G + g) * DIM + klo];
    const float* xr1 = &x[(((size_t)(n0 + 32 + col)) * G + g) * DIM + klo];
    const float* cbr[4];
#pragma unroll
    for (int t = 0; t < 4; ++t)
        cbr[t] = &cb[((size_t)g * CB + wid * 128 + t * 32 + col) * DIM + klo];

    floatx16 acc[2][4] = {};

#pragma unroll
    for (int ks = 0; ks < 8; ++ks) {
        const int d = ks * 16;
        half8 ah[2], al[2];
        split8(*(const floatx4*)(xr0 + d), *(const floatx4*)(xr0 + d + 4), ah[0], al[0]);
        split8(*(const floatx4*)(xr1 + d), *(const floatx4*)(xr1 + d + 4), ah[1], al[1]);
#pragma unroll
        for (int t = 0; t < 4; ++t) {
            half8 bh, bl;
            split8(*(const floatx4*)(cbr[t] + d), *(const floatx4*)(cbr[t] + d + 4), bh, bl);
#pragma unroll
            for (int mt = 0; mt < 2; ++mt) {
                acc[mt][t] = __builtin_amdgcn_mfma_f32_32x32x16_f16(ah[mt], bh, acc[mt][t], 0, 0, 0);
                acc[mt][t] = __builtin_amdgcn_mfma_f32_32x32x16_f16(ah[mt], bl, acc[mt][t], 0, 0, 0);
                acc[mt][t] = __builtin_amdgcn_mfma_f32_32x32x16_f16(al[mt], bh, acc[mt][t], 0, 0, 0);
            }
        }
    }

    float c2v[4];
#pragma unroll
    for (int t = 0; t < 4; ++t)
        c2v[t] = cb2h[g * CB + wid * 128 + t * 32 + col];

#pragma unroll
    for (int mt = 0; mt < 2; ++mt) {
#pragma unroll
        for (int r = 0; r < 16; ++r) {
            const int row = mt * 32 + (r & 3) + 8 * (r >> 2) + 4 * h;
            float bv = c2v[0] - acc[mt][0][r];
            int   bi = wid * 128 + col;
#pragma unroll
            for (int t = 1; t < 4; ++t) {
                float sc = c2v[t] - acc[mt][t][r];
                int   kk = wid * 128 + t * 32 + col;
                if (sc < bv) { bv = sc; bi = kk; }
            }
#pragma unroll
            for (int off = 1; off < 32; off <<= 1) {
                float ov = __shfl_xor(bv, off);
                int   oi = __shfl_xor(bi, off);
                if (ov < bv || (ov == bv && oi < bi)) { bv = ov; bi = oi; }
            }
            if (col == 0) { part_v[wid][row] = bv; part_i[wid][row] = bi; }
        }
    }
    __syncthreads();

    if (tid < FBM) {
        float bv = part_v[0][tid];
        int   bi = part_i[0][tid];
#pragma unroll
        for (int w = 1; w < 4; ++w) {
            float pv = part_v[w][tid];
            int   pi = part_i[w][tid];
            if (pv < bv || (pv == bv && pi < bi)) { bv = pv; bi = pi; }
        }
        idxs[tid] = bi;
        out[IDX_OFF + (size_t)(n0 + tid) * G + g] = (float)bi;
    }
    __syncthreads();

    float* out_xhat = out + XHAT_OFF;
    float* out_oh   = out + ONEHOT_OFF;

#pragma unroll
    for (int p = 0; p < 8; ++p) {
        int t  = tid + p * 256;
        int r  = t >> 5;
        int d4 = (t & 31) << 2;
        int k  = idxs[r];
        floatx4 v = *(const floatx4*)&cb[((size_t)g * CB + k) * DIM + d4];
        __builtin_nontemporal_store(v, (floatx4*)&out_xhat[(((size_t)(n0 + r)) * G + g) * DIM + d4]);
    }

#pragma unroll
    for (int p = 0; p < 32; ++p) {
        int t  = tid + p * 256;
        int r  = t >> 7;
        int k4 = (t & 127) << 2;
        int k  = idxs[r];
        floatx4 v;
        v.x = (k4 + 0 == k) ? 1.f : 0.f;
        v.y = (k4 + 1 == k) ? 1.f : 0.f;
        v.z = (k4 + 2 == k) ? 1.f : 0.f;
        v.w = (k4 + 3 == k) ? 1.f : 0.f;
        __builtin_nontemporal_store(v, (floatx4*)&out_oh[(((size_t)(n0 + r)) * G + g) * CB + k4]);
    }
}

extern "C" void kernel_launch(void* const* d_in, const int* in_sizes, int n_in,
                              void* d_out, int out_size, void* d_ws, size_t ws_size,
                              hipStream_t stream) {
    const float* x  = (const float*)d_in[0];
    const float* cb = (const float*)d_in[1];
    float* out = (float*)d_out;
    char*  ws  = (char*)d_ws;
    float* cb2h = (float*)ws;

    if (ws_size >= WS_NEED) {
        _Float16* cbfh = (_Float16*)(ws + CBH_OFF);
        _Float16* cbfl = (_Float16*)(ws + CBL_OFF);
        float*    pval = (float*)(ws + PVAL_OFF);
        int*      pidx = (int*)(ws + PIDX_OFF);
        cvq_cb2_kernel<<<dim3((G * CB + 255) / 256), dim3(256), 0, stream>>>(cb, cb2h);
        cvq_cbpack_kernel<<<dim3(G * CB * 16 / 256), dim3(256), 0, stream>>>(cb, cbfh, cbfl);
        cvq_phase1_kernel<<<dim3(64, G, 4), dim3(256), 0, stream>>>(x, cbfh, cbfl, cb2h, pval, pidx);
        cvq_phase2_kernel<<<dim3(N_TOT / 64, G), dim3(256), 0, stream>>>(pval, pidx, cb, out);
    } else {
        cvq_cb2_kernel<<<dim3((G * CB + 255) / 256), dim3(256), 0, stream>>>(cb, cb2h);
        cvq_main_kernel<<<dim3(N_TOT / FBM, G), dim3(256), 0, stream>>>(x, cb, cb2h, out);
    }
}

// Round 14
// 163.560 us; speedup vs baseline: 1.5649x; 1.5649x over previous
//
#include <hip/hip_runtime.h>
#include <hip/hip_bf16.h>

// Problem constants
#define N_TOT 32768
#define G 4
#define DIM 128
#define CB 512
#define BM 32            // rows per block; 8 waves, each 32 rows x 64 cols

// Output layout (floats)
#define XHAT_OFF   0
#define ONEHOT_OFF ((size_t)N_TOT * G * DIM)                      // 16777216
#define IDX_OFF    (ONEHOT_OFF + (size_t)N_TOT * G * CB)          // 83886080

// Workspace layout (bytes): cb2h + fragment-packed codebook hi/lo planes
// cbf layout: [g][colblk(16)][ks(8)][h(2)][col(32)][e(8)] fp16
#define CB2_BYTES    ((size_t)G * CB * 4)                          // 8192
#define CBH_OFF      CB2_BYTES
#define CBHALF_BYTES ((size_t)G * CB * DIM * 2)                    // 524288
#define CBL_OFF      (CBH_OFF + CBHALF_BYTES)
#define WS_NEED      (CBL_OFF + CBHALF_BYTES)                      // ~1.06 MB

typedef _Float16 half8    __attribute__((ext_vector_type(8)));
typedef float    floatx16 __attribute__((ext_vector_type(16)));
typedef float    floatx4  __attribute__((ext_vector_type(4)));

// fp32 -> (hi,lo) fp16 RN split. f = hi + lo + err, |err| <= 2^-22 |f|.
__device__ __forceinline__ void split8(floatx4 v0, floatx4 v1, half8& hi, half8& lo) {
    float f[8] = {v0.x, v0.y, v0.z, v0.w, v1.x, v1.y, v1.z, v1.w};
#pragma unroll
    for (int e = 0; e < 8; ++e) {
        _Float16 h = (_Float16)f[e];
        hi[e] = h;
        lo[e] = (_Float16)(f[e] - (float)h);
    }
}

// ---------------------------------------------------------------------------
// Prep 1: cb2h[g*CB+k] = 0.5*sum_d cb[g][k][d]^2  (validated since round 1)
// ---------------------------------------------------------------------------
__global__ void cvq_cb2_kernel(const float* __restrict__ cb, float* __restrict__ cb2h) {
    int i = blockIdx.x * 256 + threadIdx.x;
    if (i >= G * CB) return;
    const float4* p = (const float4*)&cb[(size_t)i * DIM];
    float s = 0.f;
#pragma unroll
    for (int j = 0; j < DIM / 4; ++j) {
        float4 v = p[j];
        s += v.x * v.x + v.y * v.y + v.z * v.z + v.w * v.w;
    }
    cb2h[i] = 0.5f * s;
}

// ---------------------------------------------------------------------------
// Prep 2: pack codebook into MFMA-fragment order, split hi/lo (validated r8).
// ---------------------------------------------------------------------------
__global__ void cvq_cbpack_kernel(const float* __restrict__ cb,
                                  _Float16* __restrict__ cbfh, _Float16* __restrict__ cbfl) {
    int t = blockIdx.x * 256 + threadIdx.x;    // 0..32767
    int col    = t & 31;
    int h      = (t >> 5) & 1;
    int ks     = (t >> 6) & 7;
    int colblk = (t >> 9) & 15;
    int g      = t >> 13;
    const float* src = &cb[((size_t)(g * CB + colblk * 32 + col)) * DIM + ks * 16 + h * 8];
    half8 hi, lo;
    split8(*(const floatx4*)src, *(const floatx4*)(src + 4), hi, lo);
    *(half8*)&cbfh[(size_t)t * 8] = hi;
    *(half8*)&cbfl[(size_t)t * 8] = lo;
}

// ---------------------------------------------------------------------------
// Main kernel (round-8 structure, 8 waves x 64 cols): block = (32 n-rows,
// one group g), 512 threads. Wave w -> cols w*64..+63 (2 colblks); acc[2] =
// 32 AGPR (half of r8) -> __launch_bounds__(512,4) caps 128 regs -> 4
// waves/SIMD for latency hiding (+33% vs r8's 3). cb fragment loads stay
// the validated coalesced 1024B register loads; x staged in LDS (coalesced,
// chunk XOR swizzle), split to fp16 per K-step; in-kernel streamed epilogue.
// score = 0.5*cb2[k] - cross  (same argmin as reference dist).
// Fragment layouts (gfx950 32x32x16, validated rounds 4-13):
//   A: lane l, elem e: row=l&31, k=(l>>5)*8+e ; B: col=l&31, same k
//   C: lane l, reg r:  col=l&31, row=(r&3)+8*(r>>2)+4*(l>>5)
// ---------------------------------------------------------------------------
__global__ __launch_bounds__(512, 4) void cvq_main8w_kernel(
        const float* __restrict__ x,
        const _Float16* __restrict__ cbfh, const _Float16* __restrict__ cbfl,
        const float* __restrict__ cb, const float* __restrict__ cb2h,
        float* __restrict__ out) {

    __shared__ float xstage[BM * DIM];   // 16 KB, float4-chunk swizzled
    __shared__ float part_v[8][BM];
    __shared__ int   part_i[8][BM];
    __shared__ int   idxs[BM];

    const int n0   = blockIdx.x * BM;
    const int g    = blockIdx.y;
    const int tid  = threadIdx.x;     // 0..511
    const int wid  = tid >> 6;        // wave 0..7 -> cols wid*64..+63
    const int lane = tid & 63;
    const int col  = lane & 31;
    const int h    = lane >> 5;

    // ---- stage x tile: 32 rows x 128 floats, coalesced; chunk c -> c^(r&7) ----
#pragma unroll
    for (int p = 0; p < 2; ++p) {
        int t = tid + p * 512;         // 0..1023 = 32 rows * 32 float4-chunks
        int r = t >> 5;
        int c = t & 31;
        floatx4 v = *(const floatx4*)&x[(((size_t)(n0 + r)) * G + g) * DIM + (c << 2)];
        *(floatx4*)&xstage[r * DIM + ((c ^ (r & 7)) << 2)] = v;
    }
    __syncthreads();

    const size_t cb_base = ((size_t)g * 16 + wid * 2) * 4096 + (size_t)lane * 8;

    floatx16 acc[2] = {};   // [ntile] fp32 accumulators = cross (32 AGPR)

#pragma unroll
    for (int ks = 0; ks < 8; ++ks) {
        const int c0 = ks * 4 + h * 2;
        const int s  = col & 7;
        const float* xb = &xstage[col * DIM];
        floatx4 xa = *(const floatx4*)&xb[((c0 ^ s) << 2)];
        floatx4 xc = *(const floatx4*)&xb[(((c0 + 1) ^ s) << 2)];
        half8 ah, al;
        split8(xa, xc, ah, al);
#pragma unroll
        for (int t = 0; t < 2; ++t) {
            const size_t o = cb_base + (size_t)t * 4096 + ks * 512;
            half8 bh = *(const half8*)&cbfh[o];
            half8 bl = *(const half8*)&cbfl[o];
            acc[t] = __builtin_amdgcn_mfma_f32_32x32x16_f16(ah, bh, acc[t], 0, 0, 0);
            acc[t] = __builtin_amdgcn_mfma_f32_32x32x16_f16(ah, bl, acc[t], 0, 0, 0);
            acc[t] = __builtin_amdgcn_mfma_f32_32x32x16_f16(al, bh, acc[t], 0, 0, 0);
        }
    }

    // ---- per-row argmin over this wave's 64 cols ----
    const float c2v0 = cb2h[g * CB + wid * 64 + col];
    const float c2v1 = cb2h[g * CB + wid * 64 + 32 + col];

#pragma unroll
    for (int r = 0; r < 16; ++r) {
        const int row = (r & 3) + 8 * (r >> 2) + 4 * h;   // 0..31
        float bv = c2v0 - acc[0][r];
        int   bi = wid * 64 + col;
        float s1 = c2v1 - acc[1][r];
        int   k1 = wid * 64 + 32 + col;
        if (s1 < bv) { bv = s1; bi = k1; }                // k ascending in t
#pragma unroll
        for (int off = 1; off < 32; off <<= 1) {          // stays in 32-half
            float ov = __shfl_xor(bv, off);
            int   oi = __shfl_xor(bi, off);
            if (ov < bv || (ov == bv && oi < bi)) { bv = ov; bi = oi; }
        }
        if (col == 0) { part_v[wid][row] = bv; part_i[wid][row] = bi; }
    }
    __syncthreads();

    // ---- combine the 8 waves' col-slices (ascending wave = ascending k) ----
    if (tid < BM) {
        float bv = part_v[0][tid];
        int   bi = part_i[0][tid];
#pragma unroll
        for (int w = 1; w < 8; ++w) {
            float pv = part_v[w][tid];
            int   pi = part_i[w][tid];
            if (pv < bv || (pv == bv && pi < bi)) { bv = pv; bi = pi; }
        }
        idxs[tid] = bi;
        out[IDX_OFF + (size_t)(n0 + tid) * G + g] = (float)bi;
    }
    __syncthreads();

    float* out_xhat = out + XHAT_OFF;
    float* out_oh   = out + ONEHOT_OFF;

    // ---- x_hat: 32 rows x 32 float4 (1024 / 512 thr = 2 each) ----
#pragma unroll
    for (int p = 0; p < 2; ++p) {
        int t  = tid + p * 512;
        int r  = t >> 5;
        int d4 = (t & 31) << 2;
        int k  = idxs[r];
        floatx4 v = *(const floatx4*)&cb[((size_t)g * CB + k) * DIM + d4];
        __builtin_nontemporal_store(v, (floatx4*)&out_xhat[(((size_t)(n0 + r)) * G + g) * DIM + d4]);
    }

    // ---- one_hot: 32 rows x 128 float4 (4096 / 512 thr = 8 each) ----
#pragma unroll
    for (int p = 0; p < 8; ++p) {
        int t  = tid + p * 512;
        int r  = t >> 7;
        int k4 = (t & 127) << 2;
        int k  = idxs[r];
        floatx4 v;
        v.x = (k4 + 0 == k) ? 1.f : 0.f;
        v.y = (k4 + 1 == k) ? 1.f : 0.f;
        v.z = (k4 + 2 == k) ? 1.f : 0.f;
        v.w = (k4 + 3 == k) ? 1.f : 0.f;
        __builtin_nontemporal_store(v, (floatx4*)&out_oh[(((size_t)(n0 + r)) * G + g) * CB + k4]);
    }
}

// ---------------------------------------------------------------------------
// FALLBACK (validated round-4 path, needs only 8KB ws): in-kernel splits.
// ---------------------------------------------------------------------------
#define FBM 64
__global__ __launch_bounds__(256, 2) void cvq_main_kernel(
        const float* __restrict__ x,
        const float* __restrict__ cb,
        const float* __restrict__ cb2h,
        float* __restrict__ out) {

    __shared__ float part_v[4][FBM];
    __shared__ int   part_i[4][FBM];
    __shared__ int   idxs[FBM];

    const int n0   = blockIdx.x * FBM;
    const int g    = blockIdx.y;
    const int tid  = threadIdx.x;
    const int wid  = tid >> 6;
    const int lane = tid & 63;
    const int col  = lane & 31;
    const int h    = lane >> 5;
    const int klo  = h * 8;

    const float* xr0 = &x[(((size_t)(n0 + col)) * G + g) * DIM + klo];
    const float* xr1 = &x[(((size_t)(n0 + 32 + col)) * G + g) * DIM + klo];
    const float* cbr[4];
#pragma unroll
    for (int t = 0; t < 4; ++t)
        cbr[t] = &cb[((size_t)g * CB + wid * 128 + t * 32 + col) * DIM + klo];

    floatx16 acc[2][4] = {};

#pragma unroll
    for (int ks = 0; ks < 8; ++ks) {
        const int d = ks * 16;
        half8 ah[2], al[2];
        split8(*(const floatx4*)(xr0 + d), *(const floatx4*)(xr0 + d + 4), ah[0], al[0]);
        split8(*(const floatx4*)(xr1 + d), *(const floatx4*)(xr1 + d + 4), ah[1], al[1]);
#pragma unroll
        for (int t = 0; t < 4; ++t) {
            half8 bh, bl;
            split8(*(const floatx4*)(cbr[t] + d), *(const floatx4*)(cbr[t] + d + 4), bh, bl);
#pragma unroll
            for (int mt = 0; mt < 2; ++mt) {
                acc[mt][t] = __builtin_amdgcn_mfma_f32_32x32x16_f16(ah[mt], bh, acc[mt][t], 0, 0, 0);
                acc[mt][t] = __builtin_amdgcn_mfma_f32_32x32x16_f16(ah[mt], bl, acc[mt][t], 0, 0, 0);
                acc[mt][t] = __builtin_amdgcn_mfma_f32_32x32x16_f16(al[mt], bh, acc[mt][t], 0, 0, 0);
            }
        }
    }

    float c2v[4];
#pragma unroll
    for (int t = 0; t < 4; ++t)
        c2v[t] = cb2h[g * CB + wid * 128 + t * 32 + col];

#pragma unroll
    for (int mt = 0; mt < 2; ++mt) {
#pragma unroll
        for (int r = 0; r < 16; ++r) {
            const int row = mt * 32 + (r & 3) + 8 * (r >> 2) + 4 * h;
            float bv = c2v[0] - acc[mt][0][r];
            int   bi = wid * 128 + col;
#pragma unroll
            for (int t = 1; t < 4; ++t) {
                float sc = c2v[t] - acc[mt][t][r];
                int   kk = wid * 128 + t * 32 + col;
                if (sc < bv) { bv = sc; bi = kk; }
            }
#pragma unroll
            for (int off = 1; off < 32; off <<= 1) {
                float ov = __shfl_xor(bv, off);
                int   oi = __shfl_xor(bi, off);
                if (ov < bv || (ov == bv && oi < bi)) { bv = ov; bi = oi; }
            }
            if (col == 0) { part_v[wid][row] = bv; part_i[wid][row] = bi; }
        }
    }
    __syncthreads();

    if (tid < FBM) {
        float bv = part_v[0][tid];
        int   bi = part_i[0][tid];
#pragma unroll
        for (int w = 1; w < 4; ++w) {
            float pv = part_v[w][tid];
            int   pi = part_i[w][tid];
            if (pv < bv || (pv == bv && pi < bi)) { bv = pv; bi = pi; }
        }
        idxs[tid] = bi;
        out[IDX_OFF + (size_t)(n0 + tid) * G + g] = (float)bi;
    }
    __syncthreads();

    float* out_xhat = out + XHAT_OFF;
    float* out_oh   = out + ONEHOT_OFF;

#pragma unroll
    for (int p = 0; p < 8; ++p) {
        int t  = tid + p * 256;
        int r  = t >> 5;
        int d4 = (t & 31) << 2;
        int k  = idxs[r];
        floatx4 v = *(const floatx4*)&cb[((size_t)g * CB + k) * DIM + d4];
        __builtin_nontemporal_store(v, (floatx4*)&out_xhat[(((size_t)(n0 + r)) * G + g) * DIM + d4]);
    }

#pragma unroll
    for (int p = 0; p < 32; ++p) {
        int t  = tid + p * 256;
        int r  = t >> 7;
        int k4 = (t & 127) << 2;
        int k  = idxs[r];
        floatx4 v;
        v.x = (k4 + 0 == k) ? 1.f : 0.f;
        v.y = (k4 + 1 == k) ? 1.f : 0.f;
        v.z = (k4 + 2 == k) ? 1.f : 0.f;
        v.w = (k4 + 3 == k) ? 1.f : 0.f;
        __builtin_nontemporal_store(v, (floatx4*)&out_oh[(((size_t)(n0 + r)) * G + g) * CB + k4]);
    }
}

extern "C" void kernel_launch(void* const* d_in, const int* in_sizes, int n_in,
                              void* d_out, int out_size, void* d_ws, size_t ws_size,
                              hipStream_t stream) {
    const float* x  = (const float*)d_in[0];
    const float* cb = (const float*)d_in[1];
    float* out = (float*)d_out;
    char*  ws  = (char*)d_ws;
    float* cb2h = (float*)ws;

    if (ws_size >= WS_NEED) {
        _Float16* cbfh = (_Float16*)(ws + CBH_OFF);
        _Float16* cbfl = (_Float16*)(ws + CBL_OFF);
        cvq_cb2_kernel<<<dim3((G * CB + 255) / 256), dim3(256), 0, stream>>>(cb, cb2h);
        cvq_cbpack_kernel<<<dim3(G * CB * 16 / 256), dim3(256), 0, stream>>>(cb, cbfh, cbfl);
        cvq_main8w_kernel<<<dim3(N_TOT / BM, G), dim3(512), 0, stream>>>(x, cbfh, cbfl, cb, cb2h, out);
    } else {
        cvq_cb2_kernel<<<dim3((G * CB + 255) / 256), dim3(256), 0, stream>>>(cb, cb2h);
        cvq_main_kernel<<<dim3(N_TOT / FBM, G), dim3(256), 0, stream>>>(x, cb, cb2h, out);
    }
}

// Round 15
// 156.325 us; speedup vs baseline: 1.6374x; 1.0463x over previous
//
#include <hip/hip_runtime.h>
#include <hip/hip_bf16.h>

// Problem constants
#define N_TOT 32768
#define G 4
#define DIM 128
#define CB 512
#define BM 32            // rows per block; 4 waves, each 32 rows x 128 cols

// Output layout (floats)
#define XHAT_OFF   0
#define ONEHOT_OFF ((size_t)N_TOT * G * DIM)                      // 16777216
#define IDX_OFF    (ONEHOT_OFF + (size_t)N_TOT * G * CB)          // 83886080

// Workspace layout (bytes): cb2h + fragment-packed codebook hi/lo planes
// cbf layout: [g][colblk(16)][ks(8)][h(2)][col(32)][e(8)] fp16
#define CB2_BYTES    ((size_t)G * CB * 4)                          // 8192
#define CBH_OFF      CB2_BYTES
#define CBHALF_BYTES ((size_t)G * CB * DIM * 2)                    // 524288
#define CBL_OFF      (CBH_OFF + CBHALF_BYTES)
#define WS_NEED      (CBL_OFF + CBHALF_BYTES)                      // ~1.06 MB

typedef _Float16 half8    __attribute__((ext_vector_type(8)));
typedef float    floatx16 __attribute__((ext_vector_type(16)));
typedef float    floatx4  __attribute__((ext_vector_type(4)));

// fp32 -> (hi,lo) fp16 RN split. f = hi + lo + err, |err| <= 2^-22 |f|.
__device__ __forceinline__ void split8(floatx4 v0, floatx4 v1, half8& hi, half8& lo) {
    float f[8] = {v0.x, v0.y, v0.z, v0.w, v1.x, v1.y, v1.z, v1.w};
#pragma unroll
    for (int e = 0; e < 8; ++e) {
        _Float16 h = (_Float16)f[e];
        hi[e] = h;
        lo[e] = (_Float16)(f[e] - (float)h);
    }
}

// ---------------------------------------------------------------------------
// Prep 1: cb2h[g*CB+k] = 0.5*sum_d cb[g][k][d]^2  (validated since round 1)
// ---------------------------------------------------------------------------
__global__ void cvq_cb2_kernel(const float* __restrict__ cb, float* __restrict__ cb2h) {
    int i = blockIdx.x * 256 + threadIdx.x;
    if (i >= G * CB) return;
    const float4* p = (const float4*)&cb[(size_t)i * DIM];
    float s = 0.f;
#pragma unroll
    for (int j = 0; j < DIM / 4; ++j) {
        float4 v = p[j];
        s += v.x * v.x + v.y * v.y + v.z * v.z + v.w * v.w;
    }
    cb2h[i] = 0.5f * s;
}

// ---------------------------------------------------------------------------
// Prep 2: pack codebook into MFMA-fragment order, split hi/lo (validated r8).
// ---------------------------------------------------------------------------
__global__ void cvq_cbpack_kernel(const float* __restrict__ cb,
                                  _Float16* __restrict__ cbfh, _Float16* __restrict__ cbfl) {
    int t = blockIdx.x * 256 + threadIdx.x;    // 0..32767
    int col    = t & 31;
    int h      = (t >> 5) & 1;
    int ks     = (t >> 6) & 7;
    int colblk = (t >> 9) & 15;
    int g      = t >> 13;
    const float* src = &cb[((size_t)(g * CB + colblk * 32 + col)) * DIM + ks * 16 + h * 8];
    half8 hi, lo;
    split8(*(const floatx4*)src, *(const floatx4*)(src + 4), hi, lo);
    *(half8*)&cbfh[(size_t)t * 8] = hi;
    *(half8*)&cbfl[(size_t)t * 8] = lo;
}

// ---------------------------------------------------------------------------
// Main kernel: EXACT round-8 champion structure (block = 32 rows x one g,
// 4 waves x 128 cols, acc[4], packed-cb coalesced 1024B loads, LDS x-stage
// with chunk XOR swizzle, per-ks in-kernel split, fused streamed epilogue).
// ONLY change: __launch_bounds__(256,4) — cap unified regs at 128
// (64 AGPR acc + <=64 VGPR) => 4 waves/SIMD vs r8's 3, +33% latency hiding.
// u32 offsets shrink address-register pressure to make the budget.
// score = 0.5*cb2[k] - cross  (same argmin as reference dist).
// Fragment layouts (gfx950 32x32x16, validated rounds 4-14):
//   A: lane l, elem e: row=l&31, k=(l>>5)*8+e ; B: col=l&31, same k
//   C: lane l, reg r:  col=l&31, row=(r&3)+8*(r>>2)+4*(l>>5)
// ---------------------------------------------------------------------------
__global__ __launch_bounds__(256, 4) void cvq_main4w_kernel(
        const float* __restrict__ x,
        const _Float16* __restrict__ cbfh, const _Float16* __restrict__ cbfl,
        const float* __restrict__ cb, const float* __restrict__ cb2h,
        float* __restrict__ out) {

    __shared__ float xstage[BM * DIM];   // 16 KB, float4-chunk swizzled
    __shared__ float part_v[4][BM];
    __shared__ int   part_i[4][BM];
    __shared__ int   idxs[BM];

    const int n0   = blockIdx.x * BM;
    const int g    = blockIdx.y;
    const int tid  = threadIdx.x;
    const int wid  = tid >> 6;        // wave 0..3 -> cols wid*128..+127
    const int lane = tid & 63;
    const int col  = lane & 31;
    const int h    = lane >> 5;

    // ---- stage x tile: 32 rows x 128 floats, coalesced; chunk c -> c^(r&7) ----
#pragma unroll
    for (int p = 0; p < 4; ++p) {
        int t = tid + p * 256;         // 0..1023 = 32 rows * 32 float4-chunks
        int r = t >> 5;
        int c = t & 31;
        floatx4 v = *(const floatx4*)&x[(((size_t)(n0 + r)) * G + g) * DIM + (c << 2)];
        *(floatx4*)&xstage[r * DIM + ((c ^ (r & 7)) << 2)] = v;
    }
    __syncthreads();

    // u32 offsets: cbf arrays are 256K halfs (512 KB) — fits easily
    const unsigned cb_base = (unsigned)((g * 16 + wid * 4) * 4096 + lane * 8);

    floatx16 acc[4] = {};   // [ntile] fp32 accumulators = cross (64 AGPR)

#pragma unroll 2
    for (int ks = 0; ks < 8; ++ks) {
        const int c0 = ks * 4 + h * 2;
        const int s  = col & 7;
        const float* xb = &xstage[col * DIM];
        floatx4 xa = *(const floatx4*)&xb[((c0 ^ s) << 2)];
        floatx4 xc = *(const floatx4*)&xb[(((c0 + 1) ^ s) << 2)];
        half8 ah, al;
        split8(xa, xc, ah, al);
#pragma unroll
        for (int t = 0; t < 4; ++t) {
            const unsigned o = cb_base + (unsigned)(t * 4096 + ks * 512);
            half8 bh = *(const half8*)&cbfh[o];
            half8 bl = *(const half8*)&cbfl[o];
            acc[t] = __builtin_amdgcn_mfma_f32_32x32x16_f16(ah, bh, acc[t], 0, 0, 0);
            acc[t] = __builtin_amdgcn_mfma_f32_32x32x16_f16(ah, bl, acc[t], 0, 0, 0);
            acc[t] = __builtin_amdgcn_mfma_f32_32x32x16_f16(al, bh, acc[t], 0, 0, 0);
        }
    }

    // ---- per-row argmin over this wave's 128 cols (validated r7/r8) ----
    float c2v[4];
#pragma unroll
    for (int t = 0; t < 4; ++t)
        c2v[t] = cb2h[g * CB + wid * 128 + t * 32 + col];

#pragma unroll
    for (int r = 0; r < 16; ++r) {
        const int row = (r & 3) + 8 * (r >> 2) + 4 * h;   // 0..31
        float bv = c2v[0] - acc[0][r];
        int   bi = wid * 128 + col;
#pragma unroll
        for (int t = 1; t < 4; ++t) {
            float sc = c2v[t] - acc[t][r];
            int   kk = wid * 128 + t * 32 + col;
            if (sc < bv) { bv = sc; bi = kk; }            // k ascending in t
        }
#pragma unroll
        for (int off = 1; off < 32; off <<= 1) {          // stays in 32-half
            float ov = __shfl_xor(bv, off);
            int   oi = __shfl_xor(bi, off);
            if (ov < bv || (ov == bv && oi < bi)) { bv = ov; bi = oi; }
        }
        if (col == 0) { part_v[wid][row] = bv; part_i[wid][row] = bi; }
    }
    __syncthreads();

    // ---- combine the 4 waves' col-slices (ascending wave = ascending k) ----
    if (tid < BM) {
        float bv = part_v[0][tid];
        int   bi = part_i[0][tid];
#pragma unroll
        for (int w = 1; w < 4; ++w) {
            float pv = part_v[w][tid];
            int   pi = part_i[w][tid];
            if (pv < bv || (pv == bv && pi < bi)) { bv = pv; bi = pi; }
        }
        idxs[tid] = bi;
        out[IDX_OFF + (size_t)(n0 + tid) * G + g] = (float)bi;
    }
    __syncthreads();

    float* out_xhat = out + XHAT_OFF;
    float* out_oh   = out + ONEHOT_OFF;

    // ---- x_hat: 32 rows x 32 float4, gathered from codebook (L2-hot) ----
#pragma unroll
    for (int p = 0; p < 4; ++p) {
        int t  = tid + p * 256;
        int r  = t >> 5;
        int d4 = (t & 31) << 2;
        int k  = idxs[r];
        floatx4 v = *(const floatx4*)&cb[((size_t)g * CB + k) * DIM + d4];
        __builtin_nontemporal_store(v, (floatx4*)&out_xhat[(((size_t)(n0 + r)) * G + g) * DIM + d4]);
    }

    // ---- one_hot: 32 rows x 128 float4, fused zero-fill, streaming stores ----
#pragma unroll
    for (int p = 0; p < 16; ++p) {
        int t  = tid + p * 256;
        int r  = t >> 7;
        int k4 = (t & 127) << 2;
        int k  = idxs[r];
        floatx4 v;
        v.x = (k4 + 0 == k) ? 1.f : 0.f;
        v.y = (k4 + 1 == k) ? 1.f : 0.f;
        v.z = (k4 + 2 == k) ? 1.f : 0.f;
        v.w = (k4 + 3 == k) ? 1.f : 0.f;
        __builtin_nontemporal_store(v, (floatx4*)&out_oh[(((size_t)(n0 + r)) * G + g) * CB + k4]);
    }
}

// ---------------------------------------------------------------------------
// FALLBACK (validated round-4 path, needs only 8KB ws): in-kernel splits.
// ---------------------------------------------------------------------------
#define FBM 64
__global__ __launch_bounds__(256, 2) void cvq_main_kernel(
        const float* __restrict__ x,
        const float* __restrict__ cb,
        const float* __restrict__ cb2h,
        float* __restrict__ out) {

    __shared__ float part_v[4][FBM];
    __shared__ int   part_i[4][FBM];
    __shared__ int   idxs[FBM];

    const int n0   = blockIdx.x * FBM;
    const int g    = blockIdx.y;
    const int tid  = threadIdx.x;
    const int wid  = tid >> 6;
    const int lane = tid & 63;
    const int col  = lane & 31;
    const int h    = lane >> 5;
    const int klo  = h * 8;

    const float* xr0 = &x[(((size_t)(n0 + col)) * G + g) * DIM + klo];
    const float* xr1 = &x[(((size_t)(n0 + 32 + col)) * G + g) * DIM + klo];
    const float* cbr[4];
#pragma unroll
    for (int t = 0; t < 4; ++t)
        cbr[t] = &cb[((size_t)g * CB + wid * 128 + t * 32 + col) * DIM + klo];

    floatx16 acc[2][4] = {};

#pragma unroll
    for (int ks = 0; ks < 8; ++ks) {
        const int d = ks * 16;
        half8 ah[2], al[2];
        split8(*(const floatx4*)(xr0 + d), *(const floatx4*)(xr0 + d + 4), ah[0], al[0]);
        split8(*(const floatx4*)(xr1 + d), *(const floatx4*)(xr1 + d + 4), ah[1], al[1]);
#pragma unroll
        for (int t = 0; t < 4; ++t) {
            half8 bh, bl;
            split8(*(const floatx4*)(cbr[t] + d), *(const floatx4*)(cbr[t] + d + 4), bh, bl);
#pragma unroll
            for (int mt = 0; mt < 2; ++mt) {
                acc[mt][t] = __builtin_amdgcn_mfma_f32_32x32x16_f16(ah[mt], bh, acc[mt][t], 0, 0, 0);
                acc[mt][t] = __builtin_amdgcn_mfma_f32_32x32x16_f16(ah[mt], bl, acc[mt][t], 0, 0, 0);
                acc[mt][t] = __builtin_amdgcn_mfma_f32_32x32x16_f16(al[mt], bh, acc[mt][t], 0, 0, 0);
            }
        }
    }

    float c2v[4];
#pragma unroll
    for (int t = 0; t < 4; ++t)
        c2v[t] = cb2h[g * CB + wid * 128 + t * 32 + col];

#pragma unroll
    for (int mt = 0; mt < 2; ++mt) {
#pragma unroll
        for (int r = 0; r < 16; ++r) {
            const int row = mt * 32 + (r & 3) + 8 * (r >> 2) + 4 * h;
            float bv = c2v[0] - acc[mt][0][r];
            int   bi = wid * 128 + col;
#pragma unroll
            for (int t = 1; t < 4; ++t) {
                float sc = c2v[t] - acc[mt][t][r];
                int   kk = wid * 128 + t * 32 + col;
                if (sc < bv) { bv = sc; bi = kk; }
            }
#pragma unroll
            for (int off = 1; off < 32; off <<= 1) {
                float ov = __shfl_xor(bv, off);
                int   oi = __shfl_xor(bi, off);
                if (ov < bv || (ov == bv && oi < bi)) { bv = ov; bi = oi; }
            }
            if (col == 0) { part_v[wid][row] = bv; part_i[wid][row] = bi; }
        }
    }
    __syncthreads();

    if (tid < FBM) {
        float bv = part_v[0][tid];
        int   bi = part_i[0][tid];
#pragma unroll
        for (int w = 1; w < 4; ++w) {
            float pv = part_v[w][tid];
            int   pi = part_i[w][tid];
            if (pv < bv || (pv == bv && pi < bi)) { bv = pv; bi = pi; }
        }
        idxs[tid] = bi;
        out[IDX_OFF + (size_t)(n0 + tid) * G + g] = (float)bi;
    }
    __syncthreads();

    float* out_xhat = out + XHAT_OFF;
    float* out_oh   = out + ONEHOT_OFF;

#pragma unroll
    for (int p = 0; p < 8; ++p) {
        int t  = tid + p * 256;
        int r  = t >> 5;
        int d4 = (t & 31) << 2;
        int k  = idxs[r];
        floatx4 v = *(const floatx4*)&cb[((size_t)g * CB + k) * DIM + d4];
        __builtin_nontemporal_store(v, (floatx4*)&out_xhat[(((size_t)(n0 + r)) * G + g) * DIM + d4]);
    }

#pragma unroll
    for (int p = 0; p < 32; ++p) {
        int t  = tid + p * 256;
        int r  = t >> 7;
        int k4 = (t & 127) << 2;
        int k  = idxs[r];
        floatx4 v;
        v.x = (k4 + 0 == k) ? 1.f : 0.f;
        v.y = (k4 + 1 == k) ? 1.f : 0.f;
        v.z = (k4 + 2 == k) ? 1.f : 0.f;
        v.w = (k4 + 3 == k) ? 1.f : 0.f;
        __builtin_nontemporal_store(v, (floatx4*)&out_oh[(((size_t)(n0 + r)) * G + g) * CB + k4]);
    }
}

extern "C" void kernel_launch(void* const* d_in, const int* in_sizes, int n_in,
                              void* d_out, int out_size, void* d_ws, size_t ws_size,
                              hipStream_t stream) {
    const float* x  = (const float*)d_in[0];
    const float* cb = (const float*)d_in[1];
    float* out = (float*)d_out;
    char*  ws  = (char*)d_ws;
    float* cb2h = (float*)ws;

    if (ws_size >= WS_NEED) {
        _Float16* cbfh = (_Float16*)(ws + CBH_OFF);
        _Float16* cbfl = (_Float16*)(ws + CBL_OFF);
        cvq_cb2_kernel<<<dim3((G * CB + 255) / 256), dim3(256), 0, stream>>>(cb, cb2h);
        cvq_cbpack_kernel<<<dim3(G * CB * 16 / 256), dim3(256), 0, stream>>>(cb, cbfh, cbfl);
        cvq_main4w_kernel<<<dim3(N_TOT / BM, G), dim3(256), 0, stream>>>(x, cbfh, cbfl, cb, cb2h, out);
    } else {
        cvq_cb2_kernel<<<dim3((G * CB + 255) / 256), dim3(256), 0, stream>>>(cb, cb2h);
        cvq_main_kernel<<<dim3(N_TOT / FBM, G), dim3(256), 0, stream>>>(x, cb, cb2h, out);
    }
}